// Round 1
// baseline (3090.707 us; speedup 1.0000x reference)
//
#include <hip/hip_runtime.h>

#define NN 100000
#define NE 1600000
#define D  128

// ---------------- Phase 1: scatter-add x[src] rows into agg[dst] ----------------
// 32 lanes per edge, each lane handles 4 consecutive floats (float4 gather).
__global__ __launch_bounds__(256) void gcn_scatter(
    const float* __restrict__ x, const int* __restrict__ ei,
    float* __restrict__ agg, float* __restrict__ cnt)
{
    int tid    = blockIdx.x * 256 + threadIdx.x;
    int lane   = tid & 31;
    int eg     = tid >> 5;
    int stride = (gridDim.x * 256) >> 5;
    for (int e = eg; e < NE; e += stride) {
        int src = ei[e];
        int dst = ei[NE + e];
        const float4 xv = *reinterpret_cast<const float4*>(x + (size_t)src * D + lane * 4);
        float* ap = agg + (size_t)dst * D + lane * 4;
        unsafeAtomicAdd(ap + 0, xv.x);
        unsafeAtomicAdd(ap + 1, xv.y);
        unsafeAtomicAdd(ap + 2, xv.z);
        unsafeAtomicAdd(ap + 3, xv.w);
        if (lane == 0) unsafeAtomicAdd(cnt + dst, 1.0f);
    }
}

// ---------------- Phase 2: out[n] = relu(agg[n] @ W^T / max(c,1) + b·[c>0]) -----
// 128 nodes per block, lane = node. agg tile staged in LDS (pad -> stride 133,
// gcd(5,32)=1 so column reads are bank-conflict-free). W indices are
// thread-uniform -> scalar loads; inner loop is pure v_fmac_f32 (SGPR * VGPR).
// In-place on `io` (== d_out): each block reads only its own rows into LDS
// before writing them, and no block touches another block's rows.
__global__ __launch_bounds__(128) void gcn_finish(
    float* __restrict__ io, const float* __restrict__ cnt,
    const float* __restrict__ W, const float* __restrict__ b)
{
    __shared__ float hs[128][D + 5];   // stride 133 floats
    const int nb = blockIdx.x * 128;
    const int t  = threadIdx.x;

    // cooperative coalesced tile load: 128 rows x 128 cols, float4 granularity
    for (int idx = t; idx < 128 * (D / 4); idx += 128) {
        int row  = idx >> 5;       // 32 float4 per row
        int c4   = idx & 31;
        int node = nb + row;
        float4 v = make_float4(0.f, 0.f, 0.f, 0.f);
        if (node < NN)
            v = *reinterpret_cast<const float4*>(io + (size_t)node * D + c4 * 4);
        hs[row][c4 * 4 + 0] = v.x;
        hs[row][c4 * 4 + 1] = v.y;
        hs[row][c4 * 4 + 2] = v.z;
        hs[row][c4 * 4 + 3] = v.w;
    }
    __syncthreads();

    const int node = nb + t;
    const float c  = (node < NN) ? cnt[node] : 0.f;
    const float scale = 1.0f / fmaxf(c, 1.0f);
    const bool  has   = c > 0.f;

    for (int jh = 0; jh < 2; ++jh) {
        float acc[64];
        #pragma unroll
        for (int j = 0; j < 64; ++j) acc[j] = 0.f;

        for (int ch = 0; ch < 4; ++ch) {
            float h[32];
            #pragma unroll
            for (int kk = 0; kk < 32; ++kk) h[kk] = hs[t][ch * 32 + kk];
            #pragma unroll
            for (int j = 0; j < 64; ++j) {
                const float* wr = W + (size_t)(jh * 64 + j) * D + ch * 32;  // uniform -> s_load
                #pragma unroll
                for (int kk = 0; kk < 32; ++kk)
                    acc[j] = fmaf(wr[kk], h[kk], acc[j]);
            }
        }

        if (node < NN) {
            float4* orow = reinterpret_cast<float4*>(io + (size_t)node * D + jh * 64);
            #pragma unroll
            for (int q = 0; q < 16; ++q) {
                float r[4];
                #pragma unroll
                for (int i = 0; i < 4; ++i) {
                    float bj = has ? b[jh * 64 + q * 4 + i] : 0.f;
                    r[i] = fmaxf(fmaf(acc[q * 4 + i], scale, bj), 0.f);
                }
                orow[q] = make_float4(r[0], r[1], r[2], r[3]);
            }
        }
    }
}

extern "C" void kernel_launch(void* const* d_in, const int* in_sizes, int n_in,
                              void* d_out, int out_size, void* d_ws, size_t ws_size,
                              hipStream_t stream)
{
    const float* x  = (const float*)d_in[0];
    const int*   ei = (const int*)d_in[1];
    // d_in[2] = edge_features: unused by the reference computation
    const float* W  = (const float*)d_in[3];
    const float* b  = (const float*)d_in[4];
    float* out = (float*)d_out;       // doubles as the aggregation buffer
    float* cnt = (float*)d_ws;        // N_NODES floats of scratch

    hipMemsetAsync(d_out, 0, (size_t)NN * D * sizeof(float), stream);
    hipMemsetAsync(d_ws,  0, (size_t)NN * sizeof(float), stream);

    gcn_scatter<<<4096, 256, 0, stream>>>(x, ei, out, cnt);
    gcn_finish<<<(NN + 127) / 128, 128, 0, stream>>>(out, cnt, W, b);
}

// Round 2
// 608.199 us; speedup vs baseline: 5.0817x; 5.0817x over previous
//
#include <hip/hip_runtime.h>

#define NN 100000
#define NE 1600000
#define D  128
#define SCAN_CHUNK 1024
#define NCHUNK ((NN + SCAN_CHUNK - 1) / SCAN_CHUNK)   // 98

// ---- workspace layout (bytes) ----
#define WS_COUNTS   0u
#define WS_ROWPTR   400128u                 // counts: NN*4 = 400000, padded
#define WS_PARTIALS 800768u                 // row_ptr: (NN+1)*4 = 400004, padded
#define WS_SORTED   801280u                 // partials: NCHUNK*4, padded
#define WS_NEEDED   (801280u + (unsigned)NE * 4u)   // ~7.2 MB

// =============== CSR build ===============
__global__ __launch_bounds__(256) void k_hist(const int* __restrict__ ei,
                                              unsigned* __restrict__ counts) {
    int e = blockIdx.x * 256 + threadIdx.x;
    if (e < NE) atomicAdd(&counts[ei[NE + e]], 1u);
}

__global__ __launch_bounds__(SCAN_CHUNK) void k_scan(const unsigned* __restrict__ counts,
                                                     unsigned* __restrict__ row_ptr,
                                                     unsigned* __restrict__ partials) {
    __shared__ unsigned s[SCAN_CHUNK];
    const int t = threadIdx.x;
    const int g = blockIdx.x * SCAN_CHUNK + t;
    unsigned v = (g < NN) ? counts[g] : 0u;
    s[t] = v;
    __syncthreads();
    for (int off = 1; off < SCAN_CHUNK; off <<= 1) {
        unsigned add = (t >= off) ? s[t - off] : 0u;
        __syncthreads();
        s[t] += add;
        __syncthreads();
    }
    if (g < NN) row_ptr[g] = s[t] - v;                  // exclusive
    if (t == SCAN_CHUNK - 1) partials[blockIdx.x] = s[t]; // chunk total
}

__global__ __launch_bounds__(128) void k_scan_partials(unsigned* __restrict__ partials) {
    __shared__ unsigned s[128];
    const int t = threadIdx.x;
    unsigned v = (t < NCHUNK) ? partials[t] : 0u;
    s[t] = v;
    __syncthreads();
    for (int off = 1; off < 128; off <<= 1) {
        unsigned add = (t >= off) ? s[t - off] : 0u;
        __syncthreads();
        s[t] += add;
        __syncthreads();
    }
    if (t < NCHUNK) partials[t] = s[t] - v;             // exclusive
}

__global__ __launch_bounds__(SCAN_CHUNK) void k_add_offsets(unsigned* __restrict__ row_ptr,
                                                            const unsigned* __restrict__ partials) {
    const int g = blockIdx.x * SCAN_CHUNK + threadIdx.x;
    if (g < NN) row_ptr[g] += partials[blockIdx.x];
    if (g == 0) row_ptr[NN] = NE;
}

// counts[] still holds per-node degree -> countdown cursor gives unique slots
__global__ __launch_bounds__(256) void k_place(const int* __restrict__ ei,
                                               const unsigned* __restrict__ row_ptr,
                                               unsigned* __restrict__ counts,
                                               unsigned* __restrict__ sorted_src) {
    int e = blockIdx.x * 256 + threadIdx.x;
    if (e >= NE) return;
    int d = ei[NE + e];
    unsigned pos = row_ptr[d] + atomicSub(&counts[d], 1u) - 1u;
    sorted_src[pos] = (unsigned)ei[e];
}

// =============== aggregation: wave per node, gather + register accumulate ===============
__global__ __launch_bounds__(256) void k_aggregate(const float* __restrict__ x,
                                                   const unsigned* __restrict__ row_ptr,
                                                   const unsigned* __restrict__ srt,
                                                   float* __restrict__ agg) {
    const int wave = (blockIdx.x * 256 + threadIdx.x) >> 6;
    const int lane = threadIdx.x & 63;
    if (wave >= NN) return;
    const unsigned b0 = row_ptr[wave], b1 = row_ptr[wave + 1];
    float2 a0 = make_float2(0.f, 0.f), a1 = make_float2(0.f, 0.f);
    unsigned i = b0;
    for (; i + 2 <= b1; i += 2) {
        unsigned s0 = srt[i], s1 = srt[i + 1];
        const float2 v0 = *reinterpret_cast<const float2*>(x + (size_t)s0 * D + lane * 2);
        const float2 v1 = *reinterpret_cast<const float2*>(x + (size_t)s1 * D + lane * 2);
        a0.x += v0.x; a0.y += v0.y;
        a1.x += v1.x; a1.y += v1.y;
    }
    if (i < b1) {
        unsigned s0 = srt[i];
        const float2 v0 = *reinterpret_cast<const float2*>(x + (size_t)s0 * D + lane * 2);
        a0.x += v0.x; a0.y += v0.y;
    }
    *reinterpret_cast<float2*>(agg + (size_t)wave * D + lane * 2) =
        make_float2(a0.x + a1.x, a0.y + a1.y);
}

// =============== fallback scatter (if ws too small) ===============
__global__ __launch_bounds__(256) void gcn_scatter(
    const float* __restrict__ x, const int* __restrict__ ei,
    float* __restrict__ agg, float* __restrict__ cnt)
{
    int tid    = blockIdx.x * 256 + threadIdx.x;
    int lane   = tid & 31;
    int eg     = tid >> 5;
    int stride = (gridDim.x * 256) >> 5;
    for (int e = eg; e < NE; e += stride) {
        int src = ei[e];
        int dst = ei[NE + e];
        const float4 xv = *reinterpret_cast<const float4*>(x + (size_t)src * D + lane * 4);
        float* ap = agg + (size_t)dst * D + lane * 4;
        unsafeAtomicAdd(ap + 0, xv.x);
        unsafeAtomicAdd(ap + 1, xv.y);
        unsafeAtomicAdd(ap + 2, xv.z);
        unsafeAtomicAdd(ap + 3, xv.w);
        if (lane == 0) unsafeAtomicAdd(cnt + dst, 1.0f);
    }
}

// =============== finish: out = relu(agg @ W^T / max(c,1) + b*[c>0]) ===============
// USE_ROWPTR: degree from row_ptr diff; else from float cnt array.
template <bool USE_ROWPTR>
__global__ __launch_bounds__(128) void gcn_finish(
    float* __restrict__ io, const unsigned* __restrict__ row_ptr,
    const float* __restrict__ cnt,
    const float* __restrict__ W, const float* __restrict__ b)
{
    __shared__ float hs[128][D + 5];   // stride 133: gcd(5,32)=1, conflict-free columns
    const int nb = blockIdx.x * 128;
    const int t  = threadIdx.x;

    for (int idx = t; idx < 128 * (D / 4); idx += 128) {
        int row  = idx >> 5;
        int c4   = idx & 31;
        int node = nb + row;
        float4 v = make_float4(0.f, 0.f, 0.f, 0.f);
        if (node < NN)
            v = *reinterpret_cast<const float4*>(io + (size_t)node * D + c4 * 4);
        hs[row][c4 * 4 + 0] = v.x;
        hs[row][c4 * 4 + 1] = v.y;
        hs[row][c4 * 4 + 2] = v.z;
        hs[row][c4 * 4 + 3] = v.w;
    }
    __syncthreads();

    const int node = nb + t;
    float c = 0.f;
    if (node < NN)
        c = USE_ROWPTR ? (float)(row_ptr[node + 1] - row_ptr[node]) : cnt[node];
    const float scale = 1.0f / fmaxf(c, 1.0f);
    const bool  has   = c > 0.f;

    for (int jh = 0; jh < 2; ++jh) {
        float acc[64];
        #pragma unroll
        for (int j = 0; j < 64; ++j) acc[j] = 0.f;

        for (int ch = 0; ch < 4; ++ch) {
            float h[32];
            #pragma unroll
            for (int kk = 0; kk < 32; ++kk) h[kk] = hs[t][ch * 32 + kk];
            #pragma unroll
            for (int j = 0; j < 64; ++j) {
                const float* wr = W + (size_t)(jh * 64 + j) * D + ch * 32;  // uniform -> s_load
                #pragma unroll
                for (int kk = 0; kk < 32; ++kk)
                    acc[j] = fmaf(wr[kk], h[kk], acc[j]);
            }
        }

        if (node < NN) {
            float4* orow = reinterpret_cast<float4*>(io + (size_t)node * D + jh * 64);
            #pragma unroll
            for (int q = 0; q < 16; ++q) {
                float r[4];
                #pragma unroll
                for (int i = 0; i < 4; ++i) {
                    float bj = has ? b[jh * 64 + q * 4 + i] : 0.f;
                    r[i] = fmaxf(fmaf(acc[q * 4 + i], scale, bj), 0.f);
                }
                orow[q] = make_float4(r[0], r[1], r[2], r[3]);
            }
        }
    }
}

extern "C" void kernel_launch(void* const* d_in, const int* in_sizes, int n_in,
                              void* d_out, int out_size, void* d_ws, size_t ws_size,
                              hipStream_t stream)
{
    const float* x  = (const float*)d_in[0];
    const int*   ei = (const int*)d_in[1];
    // d_in[2] = edge_features: unused by the reference computation
    const float* W  = (const float*)d_in[3];
    const float* b  = (const float*)d_in[4];
    float* out = (float*)d_out;            // doubles as the aggregation buffer

    if (ws_size >= (size_t)WS_NEEDED) {
        char* ws = (char*)d_ws;
        unsigned* counts   = (unsigned*)(ws + WS_COUNTS);
        unsigned* row_ptr  = (unsigned*)(ws + WS_ROWPTR);
        unsigned* partials = (unsigned*)(ws + WS_PARTIALS);
        unsigned* sorted   = (unsigned*)(ws + WS_SORTED);

        hipMemsetAsync(counts, 0, (size_t)NN * sizeof(unsigned), stream);
        k_hist<<<(NE + 255) / 256, 256, 0, stream>>>(ei, counts);
        k_scan<<<NCHUNK, SCAN_CHUNK, 0, stream>>>(counts, row_ptr, partials);
        k_scan_partials<<<1, 128, 0, stream>>>(partials);
        k_add_offsets<<<NCHUNK, SCAN_CHUNK, 0, stream>>>(row_ptr, partials);
        k_place<<<(NE + 255) / 256, 256, 0, stream>>>(ei, row_ptr, counts, sorted);
        k_aggregate<<<(NN * 64 + 255) / 256, 256, 0, stream>>>(x, row_ptr, sorted, out);
        gcn_finish<true><<<(NN + 127) / 128, 128, 0, stream>>>(out, row_ptr, nullptr, W, b);
    } else {
        // fallback: atomic scatter path (needs only NN floats of ws)
        float* cnt = (float*)d_ws;
        hipMemsetAsync(d_out, 0, (size_t)NN * D * sizeof(float), stream);
        hipMemsetAsync(d_ws,  0, (size_t)NN * sizeof(float), stream);
        gcn_scatter<<<4096, 256, 0, stream>>>(x, ei, out, cnt);
        gcn_finish<false><<<(NN + 127) / 128, 128, 0, stream>>>(out, nullptr, cnt, W, b);
    }
}

// Round 3
// 387.806 us; speedup vs baseline: 7.9697x; 1.5683x over previous
//
#include <hip/hip_runtime.h>

#define NN 100000
#define NE 1600000
#define D  128
#define SCAN_CHUNK 1024
#define NCHUNK ((NN + SCAN_CHUNK - 1) / SCAN_CHUNK)   // 98

// ---- workspace layout (bytes) ----
#define WS_COUNTS   0u
#define WS_ROWPTR   400128u
#define WS_PARTIALS 800768u
#define WS_SORTED   801280u
#define WS_NEEDED   (801280u + (unsigned)NE * 4u)   // ~7.2 MB

// =============== CSR build ===============
__global__ __launch_bounds__(256) void k_hist(const int* __restrict__ ei,
                                              unsigned* __restrict__ counts) {
    int e = blockIdx.x * 256 + threadIdx.x;
    if (e < NE) atomicAdd(&counts[ei[NE + e]], 1u);
}

__global__ __launch_bounds__(SCAN_CHUNK) void k_scan(const unsigned* __restrict__ counts,
                                                     unsigned* __restrict__ row_ptr,
                                                     unsigned* __restrict__ partials) {
    __shared__ unsigned s[SCAN_CHUNK];
    const int t = threadIdx.x;
    const int g = blockIdx.x * SCAN_CHUNK + t;
    unsigned v = (g < NN) ? counts[g] : 0u;
    s[t] = v;
    __syncthreads();
    for (int off = 1; off < SCAN_CHUNK; off <<= 1) {
        unsigned add = (t >= off) ? s[t - off] : 0u;
        __syncthreads();
        s[t] += add;
        __syncthreads();
    }
    if (g < NN) row_ptr[g] = s[t] - v;
    if (t == SCAN_CHUNK - 1) partials[blockIdx.x] = s[t];
}

__global__ __launch_bounds__(128) void k_scan_partials(unsigned* __restrict__ partials) {
    __shared__ unsigned s[128];
    const int t = threadIdx.x;
    unsigned v = (t < NCHUNK) ? partials[t] : 0u;
    s[t] = v;
    __syncthreads();
    for (int off = 1; off < 128; off <<= 1) {
        unsigned add = (t >= off) ? s[t - off] : 0u;
        __syncthreads();
        s[t] += add;
        __syncthreads();
    }
    if (t < NCHUNK) partials[t] = s[t] - v;
}

__global__ __launch_bounds__(SCAN_CHUNK) void k_add_offsets(unsigned* __restrict__ row_ptr,
                                                            const unsigned* __restrict__ partials) {
    const int g = blockIdx.x * SCAN_CHUNK + threadIdx.x;
    if (g < NN) row_ptr[g] += partials[blockIdx.x];
    if (g == 0) row_ptr[NN] = NE;
}

__global__ __launch_bounds__(256) void k_place(const int* __restrict__ ei,
                                               const unsigned* __restrict__ row_ptr,
                                               unsigned* __restrict__ counts,
                                               unsigned* __restrict__ sorted_src) {
    int e = blockIdx.x * 256 + threadIdx.x;
    if (e >= NE) return;
    int d = ei[NE + e];
    unsigned pos = row_ptr[d] + atomicSub(&counts[d], 1u) - 1u;
    sorted_src[pos] = (unsigned)ei[e];
}

// =============== aggregation: wave per node, 4-deep ILP ===============
__global__ __launch_bounds__(256) void k_aggregate(const float* __restrict__ x,
                                                   const unsigned* __restrict__ row_ptr,
                                                   const unsigned* __restrict__ srt,
                                                   float* __restrict__ agg) {
    const int wave = (blockIdx.x * 256 + threadIdx.x) >> 6;
    const int lane = threadIdx.x & 63;
    if (wave >= NN) return;
    const unsigned b0 = row_ptr[wave], b1 = row_ptr[wave + 1];
    float2 a0 = make_float2(0.f, 0.f), a1 = make_float2(0.f, 0.f);
    float2 a2 = make_float2(0.f, 0.f), a3 = make_float2(0.f, 0.f);
    unsigned i = b0;
    for (; i + 4 <= b1; i += 4) {
        unsigned s0 = srt[i], s1 = srt[i + 1], s2 = srt[i + 2], s3 = srt[i + 3];
        const float2 v0 = *reinterpret_cast<const float2*>(x + (size_t)s0 * D + lane * 2);
        const float2 v1 = *reinterpret_cast<const float2*>(x + (size_t)s1 * D + lane * 2);
        const float2 v2 = *reinterpret_cast<const float2*>(x + (size_t)s2 * D + lane * 2);
        const float2 v3 = *reinterpret_cast<const float2*>(x + (size_t)s3 * D + lane * 2);
        a0.x += v0.x; a0.y += v0.y;
        a1.x += v1.x; a1.y += v1.y;
        a2.x += v2.x; a2.y += v2.y;
        a3.x += v3.x; a3.y += v3.y;
    }
    for (; i < b1; ++i) {
        unsigned s0 = srt[i];
        const float2 v0 = *reinterpret_cast<const float2*>(x + (size_t)s0 * D + lane * 2);
        a0.x += v0.x; a0.y += v0.y;
    }
    *reinterpret_cast<float2*>(agg + (size_t)wave * D + lane * 2) =
        make_float2(a0.x + a1.x + a2.x + a3.x, a0.y + a1.y + a2.y + a3.y);
}

// =============== fallback scatter (if ws too small) ===============
__global__ __launch_bounds__(256) void gcn_scatter(
    const float* __restrict__ x, const int* __restrict__ ei,
    float* __restrict__ agg, float* __restrict__ cnt)
{
    int tid    = blockIdx.x * 256 + threadIdx.x;
    int lane   = tid & 31;
    int eg     = tid >> 5;
    int stride = (gridDim.x * 256) >> 5;
    for (int e = eg; e < NE; e += stride) {
        int src = ei[e];
        int dst = ei[NE + e];
        const float4 xv = *reinterpret_cast<const float4*>(x + (size_t)src * D + lane * 4);
        float* ap = agg + (size_t)dst * D + lane * 4;
        unsafeAtomicAdd(ap + 0, xv.x);
        unsafeAtomicAdd(ap + 1, xv.y);
        unsafeAtomicAdd(ap + 2, xv.z);
        unsafeAtomicAdd(ap + 3, xv.w);
        if (lane == 0) unsafeAtomicAdd(cnt + dst, 1.0f);
    }
}

// =============== finish GEMM: out = relu((A @ W^T) * sc + b*has) ===============
// Tile 128 nodes x 128 outs, 256 threads, 8x8 micro-tile. A and W staged in LDS
// k-major (transposed). Storage map: element (k, x) -> k*128 + (x ^ ((k&12)<<1)).
// The XOR keeps 16B blocks intact (read side: aligned b128, conflict-free) and
// spreads the transpose column-writes across 8 banks instead of 2.
template <bool USE_ROWPTR>
__global__ __launch_bounds__(256, 1) void gcn_gemm(
    float* __restrict__ io, const unsigned* __restrict__ rp,
    const float* __restrict__ cnt,
    const float* __restrict__ W, const float* __restrict__ b)
{
    __shared__ float At[128 * 128];
    __shared__ float Wt[128 * 128];
    __shared__ float sc[128];
    __shared__ float hasf[128];

    const int t  = threadIdx.x;
    const int nb = blockIdx.x * 128;

    // stage W transposed: coalesced float4 reads, XOR-swizzled scalar writes
    for (int i = t; i < 128 * 32; i += 256) {
        int j = i >> 5, c4 = i & 31;
        const float4 v = *reinterpret_cast<const float4*>(W + (size_t)j * D + c4 * 4);
        int k0 = c4 * 4;
        Wt[(k0 + 0) * 128 + (j ^ (((k0 + 0) & 12) << 1))] = v.x;
        Wt[(k0 + 1) * 128 + (j ^ (((k0 + 1) & 12) << 1))] = v.y;
        Wt[(k0 + 2) * 128 + (j ^ (((k0 + 2) & 12) << 1))] = v.z;
        Wt[(k0 + 3) * 128 + (j ^ (((k0 + 3) & 12) << 1))] = v.w;
    }
    // stage A transposed
    for (int i = t; i < 128 * 32; i += 256) {
        int n = i >> 5, c4 = i & 31;
        int node = nb + n;
        float4 v = make_float4(0.f, 0.f, 0.f, 0.f);
        if (node < NN)
            v = *reinterpret_cast<const float4*>(io + (size_t)node * D + c4 * 4);
        int k0 = c4 * 4;
        At[(k0 + 0) * 128 + (n ^ (((k0 + 0) & 12) << 1))] = v.x;
        At[(k0 + 1) * 128 + (n ^ (((k0 + 1) & 12) << 1))] = v.y;
        At[(k0 + 2) * 128 + (n ^ (((k0 + 2) & 12) << 1))] = v.z;
        At[(k0 + 3) * 128 + (n ^ (((k0 + 3) & 12) << 1))] = v.w;
    }
    // per-node scale / has-bias flags
    if (t < 128) {
        int node = nb + t;
        float c = 0.f;
        if (node < NN)
            c = USE_ROWPTR ? (float)(rp[node + 1] - rp[node]) : cnt[node];
        sc[t]   = 1.0f / fmaxf(c, 1.0f);
        hasf[t] = (c > 0.f) ? 1.0f : 0.0f;
    }
    __syncthreads();

    const int tn = t >> 4;    // node group 0..15 -> nodes tn*8..+7
    const int tj = t & 15;    // out  group 0..15 -> outs  tj*8..+7

    float bj[8];
    {
        const float4 b0 = *reinterpret_cast<const float4*>(b + tj * 8);
        const float4 b1 = *reinterpret_cast<const float4*>(b + tj * 8 + 4);
        bj[0]=b0.x; bj[1]=b0.y; bj[2]=b0.z; bj[3]=b0.w;
        bj[4]=b1.x; bj[5]=b1.y; bj[6]=b1.z; bj[7]=b1.w;
    }

    float acc[8][8];
    #pragma unroll
    for (int i = 0; i < 8; ++i)
        #pragma unroll
        for (int j = 0; j < 8; ++j) acc[i][j] = 0.f;

    #pragma unroll 2
    for (int k = 0; k < 128; ++k) {
        const int g = (k & 12) << 1;
        const float* Ar = At + k * 128;
        const float* Wr = Wt + k * 128;
        const float4 a0 = *reinterpret_cast<const float4*>(Ar + ((tn * 8) ^ g));
        const float4 a1 = *reinterpret_cast<const float4*>(Ar + ((tn * 8 + 4) ^ g));
        const float4 w0 = *reinterpret_cast<const float4*>(Wr + ((tj * 8) ^ g));
        const float4 w1 = *reinterpret_cast<const float4*>(Wr + ((tj * 8 + 4) ^ g));
        const float a[8] = {a0.x,a0.y,a0.z,a0.w,a1.x,a1.y,a1.z,a1.w};
        const float w[8] = {w0.x,w0.y,w0.z,w0.w,w1.x,w1.y,w1.z,w1.w};
        #pragma unroll
        for (int i = 0; i < 8; ++i)
            #pragma unroll
            for (int j = 0; j < 8; ++j)
                acc[i][j] = fmaf(a[i], w[j], acc[i][j]);
    }

    #pragma unroll
    for (int i = 0; i < 8; ++i) {
        const int node = nb + tn * 8 + i;
        if (node >= NN) continue;
        const float s  = sc[tn * 8 + i];
        const float hf = hasf[tn * 8 + i];
        float r[8];
        #pragma unroll
        for (int j = 0; j < 8; ++j)
            r[j] = fmaxf(fmaf(acc[i][j], s, bj[j] * hf), 0.f);
        float4* orow = reinterpret_cast<float4*>(io + (size_t)node * D + tj * 8);
        orow[0] = make_float4(r[0], r[1], r[2], r[3]);
        orow[1] = make_float4(r[4], r[5], r[6], r[7]);
    }
}

extern "C" void kernel_launch(void* const* d_in, const int* in_sizes, int n_in,
                              void* d_out, int out_size, void* d_ws, size_t ws_size,
                              hipStream_t stream)
{
    const float* x  = (const float*)d_in[0];
    const int*   ei = (const int*)d_in[1];
    // d_in[2] = edge_features: unused by the reference computation
    const float* W  = (const float*)d_in[3];
    const float* b  = (const float*)d_in[4];
    float* out = (float*)d_out;            // doubles as the aggregation buffer

    const int ngemm = (NN + 127) / 128;

    if (ws_size >= (size_t)WS_NEEDED) {
        char* ws = (char*)d_ws;
        unsigned* counts   = (unsigned*)(ws + WS_COUNTS);
        unsigned* row_ptr  = (unsigned*)(ws + WS_ROWPTR);
        unsigned* partials = (unsigned*)(ws + WS_PARTIALS);
        unsigned* sorted   = (unsigned*)(ws + WS_SORTED);

        hipMemsetAsync(counts, 0, (size_t)NN * sizeof(unsigned), stream);
        k_hist<<<(NE + 255) / 256, 256, 0, stream>>>(ei, counts);
        k_scan<<<NCHUNK, SCAN_CHUNK, 0, stream>>>(counts, row_ptr, partials);
        k_scan_partials<<<1, 128, 0, stream>>>(partials);
        k_add_offsets<<<NCHUNK, SCAN_CHUNK, 0, stream>>>(row_ptr, partials);
        k_place<<<(NE + 255) / 256, 256, 0, stream>>>(ei, row_ptr, counts, sorted);
        k_aggregate<<<(NN * 64 + 255) / 256, 256, 0, stream>>>(x, row_ptr, sorted, out);
        gcn_gemm<true><<<ngemm, 256, 0, stream>>>(out, row_ptr, nullptr, W, b);
    } else {
        float* cnt = (float*)d_ws;
        hipMemsetAsync(d_out, 0, (size_t)NN * D * sizeof(float), stream);
        hipMemsetAsync(d_ws,  0, (size_t)NN * sizeof(float), stream);
        gcn_scatter<<<4096, 256, 0, stream>>>(x, ei, out, cnt);
        gcn_gemm<false><<<ngemm, 256, 0, stream>>>(out, nullptr, cnt, W, b);
    }
}

// Round 4
// 278.943 us; speedup vs baseline: 11.0801x; 1.3903x over previous
//
#include <hip/hip_runtime.h>

#define NN 100000
#define NE 1600000
#define D  128
#define SCAN_CHUNK 1024
#define NCHUNK ((NN + SCAN_CHUNK - 1) / SCAN_CHUNK)   // 98

// ---- workspace layout (bytes) ----
#define WS_COUNTS   0u
#define WS_ROWPTR   400128u
#define WS_PARTIALS 800768u
#define WS_SORTED   801280u
#define WS_BH       7201280u                         // 16*128*8 bf16 = 32 KB
#define WS_XH       7234048u                         // NN*D bf16 = 25.6 MB
#define WS_MID      7201280u
#define WS_FULL     (7234048u + (unsigned)NN * (unsigned)D * 2u)  // 32,834,048

typedef __attribute__((ext_vector_type(8))) short bf16x8;
typedef __attribute__((ext_vector_type(4))) float f32x4;

__device__ __forceinline__ unsigned short f2bf(float f) {   // RNE f32 -> bf16
    union { float f; unsigned u; } v; v.f = f;
    unsigned r = v.u + 0x7fffu + ((v.u >> 16) & 1u);
    return (unsigned short)(r >> 16);
}
__device__ __forceinline__ float bfbits(unsigned hi) {      // bf16 bits in high half -> f32
    union { unsigned u; float f; } v; v.u = hi; return v.f;
}

// =============== CSR build ===============
__global__ __launch_bounds__(256) void k_hist(const int* __restrict__ ei,
                                              unsigned* __restrict__ counts) {
    int e = blockIdx.x * 256 + threadIdx.x;
    if (e < NE) atomicAdd(&counts[ei[NE + e]], 1u);
}

__global__ __launch_bounds__(SCAN_CHUNK) void k_scan(const unsigned* __restrict__ counts,
                                                     unsigned* __restrict__ row_ptr,
                                                     unsigned* __restrict__ partials) {
    __shared__ unsigned s[SCAN_CHUNK];
    const int t = threadIdx.x;
    const int g = blockIdx.x * SCAN_CHUNK + t;
    unsigned v = (g < NN) ? counts[g] : 0u;
    s[t] = v;
    __syncthreads();
    for (int off = 1; off < SCAN_CHUNK; off <<= 1) {
        unsigned add = (t >= off) ? s[t - off] : 0u;
        __syncthreads();
        s[t] += add;
        __syncthreads();
    }
    if (g < NN) row_ptr[g] = s[t] - v;
    if (t == SCAN_CHUNK - 1) partials[blockIdx.x] = s[t];
}

__global__ __launch_bounds__(128) void k_scan_partials(unsigned* __restrict__ partials) {
    __shared__ unsigned s[128];
    const int t = threadIdx.x;
    unsigned v = (t < NCHUNK) ? partials[t] : 0u;
    s[t] = v;
    __syncthreads();
    for (int off = 1; off < 128; off <<= 1) {
        unsigned add = (t >= off) ? s[t - off] : 0u;
        __syncthreads();
        s[t] += add;
        __syncthreads();
    }
    if (t < NCHUNK) partials[t] = s[t] - v;
}

__global__ __launch_bounds__(SCAN_CHUNK) void k_add_offsets(unsigned* __restrict__ row_ptr,
                                                            const unsigned* __restrict__ partials) {
    const int g = blockIdx.x * SCAN_CHUNK + threadIdx.x;
    if (g < NN) row_ptr[g] += partials[blockIdx.x];
    if (g == 0) row_ptr[NN] = NE;
}

__global__ __launch_bounds__(256) void k_place(const int* __restrict__ ei,
                                               const unsigned* __restrict__ row_ptr,
                                               unsigned* __restrict__ counts,
                                               unsigned* __restrict__ sorted_src) {
    int e = blockIdx.x * 256 + threadIdx.x;
    if (e >= NE) return;
    int d = ei[NE + e];
    unsigned pos = row_ptr[d] + atomicSub(&counts[d], 1u) - 1u;
    sorted_src[pos] = (unsigned)ei[e];
}

// =============== casts ===============
__global__ __launch_bounds__(256) void k_cast_x(const float4* __restrict__ x4,
                                                uint4* __restrict__ xh4) {
    int i = blockIdx.x * 256 + threadIdx.x;   // one 16B bf16 group = 8 floats
    if (i >= NN * D / 8) return;
    const float4 v0 = x4[i * 2], v1 = x4[i * 2 + 1];
    uint4 o;
    o.x = f2bf(v0.x) | ((unsigned)f2bf(v0.y) << 16);
    o.y = f2bf(v0.z) | ((unsigned)f2bf(v0.w) << 16);
    o.z = f2bf(v1.x) | ((unsigned)f2bf(v1.y) << 16);
    o.w = f2bf(v1.z) | ((unsigned)f2bf(v1.w) << 16);
    xh4[i] = o;
}

// Bh element (kc, j, e) = W[j][kc*8+e], kc=0..15, e=0..7 -> B-fragment reads contiguous
__global__ __launch_bounds__(256) void k_cast_W(const float* __restrict__ W,
                                                unsigned short* __restrict__ Bh) {
    int idx = blockIdx.x * 256 + threadIdx.x;   // idx = j*16 + kc
    if (idx >= 128 * 16) return;
    int j = idx >> 4, kc = idx & 15;
    const float4 w0 = *(const float4*)(W + (size_t)j * D + kc * 8);
    const float4 w1 = *(const float4*)(W + (size_t)j * D + kc * 8 + 4);
    unsigned short* o = Bh + ((size_t)(kc * 128 + j)) * 8;
    o[0] = f2bf(w0.x); o[1] = f2bf(w0.y); o[2] = f2bf(w0.z); o[3] = f2bf(w0.w);
    o[4] = f2bf(w1.x); o[5] = f2bf(w1.y); o[6] = f2bf(w1.z); o[7] = f2bf(w1.w);
}

// =============== aggregation: wave per node, bf16 gather, 2 rows/instr ===============
__global__ __launch_bounds__(256) void k_aggregate_h(const unsigned short* __restrict__ xh,
                                                     const unsigned* __restrict__ rp,
                                                     const unsigned* __restrict__ srt,
                                                     float* __restrict__ agg) {
    const int wave = (blockIdx.x * 256 + threadIdx.x) >> 6;
    const int lane = threadIdx.x & 63;
    if (wave >= NN) return;
    const int half = lane >> 5;      // half-waves take alternating edges
    const int c8   = lane & 31;      // cols c8*4 .. c8*4+3
    const unsigned b0 = rp[wave], b1 = rp[wave + 1];

    float a0=0.f,a1=0.f,a2=0.f,a3=0.f, c0=0.f,c1=0.f,c2=0.f,c3=0.f;
    unsigned i = b0 + half;
    for (; i + 6 < b1; i += 8) {     // 4 rows per half-wave in flight
        const uint2 p0 = *(const uint2*)(xh + (size_t)srt[i]     * D + c8 * 4);
        const uint2 p1 = *(const uint2*)(xh + (size_t)srt[i + 2] * D + c8 * 4);
        const uint2 p2 = *(const uint2*)(xh + (size_t)srt[i + 4] * D + c8 * 4);
        const uint2 p3 = *(const uint2*)(xh + (size_t)srt[i + 6] * D + c8 * 4);
        a0 += bfbits(p0.x << 16); a1 += bfbits(p0.x & 0xffff0000u);
        a2 += bfbits(p0.y << 16); a3 += bfbits(p0.y & 0xffff0000u);
        c0 += bfbits(p1.x << 16); c1 += bfbits(p1.x & 0xffff0000u);
        c2 += bfbits(p1.y << 16); c3 += bfbits(p1.y & 0xffff0000u);
        a0 += bfbits(p2.x << 16); a1 += bfbits(p2.x & 0xffff0000u);
        a2 += bfbits(p2.y << 16); a3 += bfbits(p2.y & 0xffff0000u);
        c0 += bfbits(p3.x << 16); c1 += bfbits(p3.x & 0xffff0000u);
        c2 += bfbits(p3.y << 16); c3 += bfbits(p3.y & 0xffff0000u);
    }
    for (; i < b1; i += 2) {
        const uint2 p = *(const uint2*)(xh + (size_t)srt[i] * D + c8 * 4);
        a0 += bfbits(p.x << 16); a1 += bfbits(p.x & 0xffff0000u);
        a2 += bfbits(p.y << 16); a3 += bfbits(p.y & 0xffff0000u);
    }
    float s0 = a0 + c0, s1 = a1 + c1, s2 = a2 + c2, s3 = a3 + c3;
    s0 += __shfl_xor(s0, 32); s1 += __shfl_xor(s1, 32);
    s2 += __shfl_xor(s2, 32); s3 += __shfl_xor(s3, 32);
    if (half == 0)
        *(float4*)(agg + (size_t)wave * D + c8 * 4) = make_float4(s0, s1, s2, s3);
}

// =============== f32 aggregate (mid-path fallback) ===============
__global__ __launch_bounds__(256) void k_aggregate(const float* __restrict__ x,
                                                   const unsigned* __restrict__ row_ptr,
                                                   const unsigned* __restrict__ srt,
                                                   float* __restrict__ agg) {
    const int wave = (blockIdx.x * 256 + threadIdx.x) >> 6;
    const int lane = threadIdx.x & 63;
    if (wave >= NN) return;
    const unsigned b0 = row_ptr[wave], b1 = row_ptr[wave + 1];
    float2 a0 = make_float2(0.f, 0.f), a1 = make_float2(0.f, 0.f);
    float2 a2 = make_float2(0.f, 0.f), a3 = make_float2(0.f, 0.f);
    unsigned i = b0;
    for (; i + 4 <= b1; i += 4) {
        unsigned s0 = srt[i], s1 = srt[i + 1], s2 = srt[i + 2], s3 = srt[i + 3];
        const float2 v0 = *reinterpret_cast<const float2*>(x + (size_t)s0 * D + lane * 2);
        const float2 v1 = *reinterpret_cast<const float2*>(x + (size_t)s1 * D + lane * 2);
        const float2 v2 = *reinterpret_cast<const float2*>(x + (size_t)s2 * D + lane * 2);
        const float2 v3 = *reinterpret_cast<const float2*>(x + (size_t)s3 * D + lane * 2);
        a0.x += v0.x; a0.y += v0.y;
        a1.x += v1.x; a1.y += v1.y;
        a2.x += v2.x; a2.y += v2.y;
        a3.x += v3.x; a3.y += v3.y;
    }
    for (; i < b1; ++i) {
        unsigned s0 = srt[i];
        const float2 v0 = *reinterpret_cast<const float2*>(x + (size_t)s0 * D + lane * 2);
        a0.x += v0.x; a0.y += v0.y;
    }
    *reinterpret_cast<float2*>(agg + (size_t)wave * D + lane * 2) =
        make_float2(a0.x + a1.x + a2.x + a3.x, a0.y + a1.y + a2.y + a3.y);
}

// =============== fallback scatter (ws too small for CSR) ===============
__global__ __launch_bounds__(256) void gcn_scatter(
    const float* __restrict__ x, const int* __restrict__ ei,
    float* __restrict__ agg, float* __restrict__ cnt)
{
    int tid    = blockIdx.x * 256 + threadIdx.x;
    int lane   = tid & 31;
    int eg     = tid >> 5;
    int stride = (gridDim.x * 256) >> 5;
    for (int e = eg; e < NE; e += stride) {
        int src = ei[e];
        int dst = ei[NE + e];
        const float4 xv = *reinterpret_cast<const float4*>(x + (size_t)src * D + lane * 4);
        float* ap = agg + (size_t)dst * D + lane * 4;
        unsafeAtomicAdd(ap + 0, xv.x);
        unsafeAtomicAdd(ap + 1, xv.y);
        unsafeAtomicAdd(ap + 2, xv.z);
        unsafeAtomicAdd(ap + 3, xv.w);
        if (lane == 0) unsafeAtomicAdd(cnt + dst, 1.0f);
    }
}

// =============== MFMA finish GEMM (full path) ===============
// out[n][j] = relu( (sum_k agg[n][k]*W[j][k]) * sc[n] + b[j]*has[n] )
// A staged bf16 + XOR-swizzled granules; B copied linear from pre-arranged Bh.
// mfma_f32_16x16x32_bf16: A row = lane&15, B col = lane&15, k-chunk = lane>>4
// (k-permutation cancels A/B-side); D: col = lane&15, row = (lane>>4)*4 + reg.
__global__ __launch_bounds__(256) void gcn_gemm_mfma(
    float* __restrict__ io, const unsigned* __restrict__ rp,
    const unsigned short* __restrict__ Bh, const float* __restrict__ b)
{
    __shared__ unsigned short As[128 * 128];   // 32 KB, swizzled granules
    __shared__ unsigned short Bs[128 * 128];   // 32 KB, linear [kc][j][8]
    __shared__ float scs[128], hass[128], bbs[128];

    const int t  = threadIdx.x;
    const int nb = blockIdx.x * 128;

    // stage B: straight 32 KB copy
    {
        const uint4* src = (const uint4*)Bh;
        uint4* dst = (uint4*)Bs;
        #pragma unroll
        for (int i = 0; i < 8; ++i) dst[t + i * 256] = src[t + i * 256];
    }
    // stage A: read agg f32, convert to bf16, swizzled 16B granule writes
    for (int gid = t; gid < 2048; gid += 256) {
        const int m = gid >> 4, g = gid & 15;
        const int node = nb + m;
        float4 v0 = make_float4(0.f,0.f,0.f,0.f), v1 = v0;
        if (node < NN) {
            v0 = *(const float4*)(io + (size_t)node * D + g * 8);
            v1 = *(const float4*)(io + (size_t)node * D + g * 8 + 4);
        }
        uint4 o;
        o.x = f2bf(v0.x) | ((unsigned)f2bf(v0.y) << 16);
        o.y = f2bf(v0.z) | ((unsigned)f2bf(v0.w) << 16);
        o.z = f2bf(v1.x) | ((unsigned)f2bf(v1.y) << 16);
        o.w = f2bf(v1.z) | ((unsigned)f2bf(v1.w) << 16);
        *(uint4*)(As + (size_t)m * 128 + ((g ^ (m & 15)) * 8)) = o;
    }
    if (t < 128) {
        const int node = nb + t;
        float c = (node < NN) ? (float)(rp[node + 1] - rp[node]) : 0.f;
        scs[t]  = 1.f / fmaxf(c, 1.f);
        hass[t] = (c > 0.f) ? 1.f : 0.f;
        bbs[t]  = b[t];
    }
    __syncthreads();

    const int w = t >> 6, lane = t & 63;
    const int wm = (w & 1) * 64, wn = (w >> 1) * 64;   // wave quadrant
    const int lr = lane & 15, lc = lane >> 4;

    f32x4 acc[4][4];
    #pragma unroll
    for (int mi = 0; mi < 4; ++mi)
        #pragma unroll
        for (int ni = 0; ni < 4; ++ni) acc[mi][ni] = (f32x4){0.f, 0.f, 0.f, 0.f};

    #pragma unroll
    for (int ks = 0; ks < 4; ++ks) {
        bf16x8 af[4], bg[4];
        #pragma unroll
        for (int mi = 0; mi < 4; ++mi) {
            const int m = wm + mi * 16 + lr;
            const int g = ks * 4 + lc;
            af[mi] = *(const bf16x8*)(As + (size_t)m * 128 + ((g ^ (m & 15)) * 8));
        }
        #pragma unroll
        for (int ni = 0; ni < 4; ++ni) {
            const int j  = wn + ni * 16 + lr;
            const int kc = ks * 4 + lc;
            bg[ni] = *(const bf16x8*)(Bs + ((size_t)(kc * 128 + j)) * 8);
        }
        #pragma unroll
        for (int mi = 0; mi < 4; ++mi)
            #pragma unroll
            for (int ni = 0; ni < 4; ++ni)
                acc[mi][ni] = __builtin_amdgcn_mfma_f32_16x16x32_bf16(
                    af[mi], bg[ni], acc[mi][ni], 0, 0, 0);
    }

    #pragma unroll
    for (int mi = 0; mi < 4; ++mi) {
        #pragma unroll
        for (int reg = 0; reg < 4; ++reg) {
            const int rl   = wm + mi * 16 + lc * 4 + reg;
            const int node = nb + rl;
            if (node >= NN) continue;
            const float s = scs[rl], hf = hass[rl];
            #pragma unroll
            for (int ni = 0; ni < 4; ++ni) {
                const int jl = wn + ni * 16 + lr;
                io[(size_t)node * D + jl] =
                    fmaxf(fmaf(acc[mi][ni][reg], s, bbs[jl] * hf), 0.f);
            }
        }
    }
}

// =============== VALU finish GEMM (fallback paths) ===============
template <bool USE_ROWPTR>
__global__ __launch_bounds__(256, 1) void gcn_gemm(
    float* __restrict__ io, const unsigned* __restrict__ rp,
    const float* __restrict__ cnt,
    const float* __restrict__ W, const float* __restrict__ b)
{
    __shared__ float At[128 * 128];
    __shared__ float Wt[128 * 128];
    __shared__ float sc[128];
    __shared__ float hasf[128];

    const int t  = threadIdx.x;
    const int nb = blockIdx.x * 128;

    for (int i = t; i < 128 * 32; i += 256) {
        int j = i >> 5, c4 = i & 31;
        const float4 v = *reinterpret_cast<const float4*>(W + (size_t)j * D + c4 * 4);
        int k0 = c4 * 4;
        Wt[(k0 + 0) * 128 + (j ^ (((k0 + 0) & 12) << 1))] = v.x;
        Wt[(k0 + 1) * 128 + (j ^ (((k0 + 1) & 12) << 1))] = v.y;
        Wt[(k0 + 2) * 128 + (j ^ (((k0 + 2) & 12) << 1))] = v.z;
        Wt[(k0 + 3) * 128 + (j ^ (((k0 + 3) & 12) << 1))] = v.w;
    }
    for (int i = t; i < 128 * 32; i += 256) {
        int n = i >> 5, c4 = i & 31;
        int node = nb + n;
        float4 v = make_float4(0.f, 0.f, 0.f, 0.f);
        if (node < NN)
            v = *reinterpret_cast<const float4*>(io + (size_t)node * D + c4 * 4);
        int k0 = c4 * 4;
        At[(k0 + 0) * 128 + (n ^ (((k0 + 0) & 12) << 1))] = v.x;
        At[(k0 + 1) * 128 + (n ^ (((k0 + 1) & 12) << 1))] = v.y;
        At[(k0 + 2) * 128 + (n ^ (((k0 + 2) & 12) << 1))] = v.z;
        At[(k0 + 3) * 128 + (n ^ (((k0 + 3) & 12) << 1))] = v.w;
    }
    if (t < 128) {
        int node = nb + t;
        float c = 0.f;
        if (node < NN)
            c = USE_ROWPTR ? (float)(rp[node + 1] - rp[node]) : cnt[node];
        sc[t]   = 1.0f / fmaxf(c, 1.0f);
        hasf[t] = (c > 0.f) ? 1.0f : 0.0f;
    }
    __syncthreads();

    const int tn = t >> 4;
    const int tj = t & 15;

    float bj[8];
    {
        const float4 b0 = *reinterpret_cast<const float4*>(b + tj * 8);
        const float4 b1 = *reinterpret_cast<const float4*>(b + tj * 8 + 4);
        bj[0]=b0.x; bj[1]=b0.y; bj[2]=b0.z; bj[3]=b0.w;
        bj[4]=b1.x; bj[5]=b1.y; bj[6]=b1.z; bj[7]=b1.w;
    }

    float acc[8][8];
    #pragma unroll
    for (int i = 0; i < 8; ++i)
        #pragma unroll
        for (int j = 0; j < 8; ++j) acc[i][j] = 0.f;

    #pragma unroll 2
    for (int k = 0; k < 128; ++k) {
        const int g = (k & 12) << 1;
        const float* Ar = At + k * 128;
        const float* Wr = Wt + k * 128;
        const float4 a0 = *reinterpret_cast<const float4*>(Ar + ((tn * 8) ^ g));
        const float4 a1 = *reinterpret_cast<const float4*>(Ar + ((tn * 8 + 4) ^ g));
        const float4 w0 = *reinterpret_cast<const float4*>(Wr + ((tj * 8) ^ g));
        const float4 w1 = *reinterpret_cast<const float4*>(Wr + ((tj * 8 + 4) ^ g));
        const float a[8] = {a0.x,a0.y,a0.z,a0.w,a1.x,a1.y,a1.z,a1.w};
        const float wv[8] = {w0.x,w0.y,w0.z,w0.w,w1.x,w1.y,w1.z,w1.w};
        #pragma unroll
        for (int i = 0; i < 8; ++i)
            #pragma unroll
            for (int j = 0; j < 8; ++j)
                acc[i][j] = fmaf(a[i], wv[j], acc[i][j]);
    }

    #pragma unroll
    for (int i = 0; i < 8; ++i) {
        const int node = nb + tn * 8 + i;
        if (node >= NN) continue;
        const float s  = sc[tn * 8 + i];
        const float hf = hasf[tn * 8 + i];
        float r[8];
        #pragma unroll
        for (int j = 0; j < 8; ++j)
            r[j] = fmaxf(fmaf(acc[i][j], s, bj[j] * hf), 0.f);
        float4* orow = reinterpret_cast<float4*>(io + (size_t)node * D + tj * 8);
        orow[0] = make_float4(r[0], r[1], r[2], r[3]);
        orow[1] = make_float4(r[4], r[5], r[6], r[7]);
    }
}

extern "C" void kernel_launch(void* const* d_in, const int* in_sizes, int n_in,
                              void* d_out, int out_size, void* d_ws, size_t ws_size,
                              hipStream_t stream)
{
    const float* x  = (const float*)d_in[0];
    const int*   ei = (const int*)d_in[1];
    // d_in[2] = edge_features: unused by the reference computation
    const float* W  = (const float*)d_in[3];
    const float* b  = (const float*)d_in[4];
    float* out = (float*)d_out;            // doubles as the aggregation buffer

    const int ngemm = (NN + 127) / 128;

    if (ws_size >= (size_t)WS_FULL) {
        char* ws = (char*)d_ws;
        unsigned* counts   = (unsigned*)(ws + WS_COUNTS);
        unsigned* row_ptr  = (unsigned*)(ws + WS_ROWPTR);
        unsigned* partials = (unsigned*)(ws + WS_PARTIALS);
        unsigned* sorted   = (unsigned*)(ws + WS_SORTED);
        unsigned short* Bh = (unsigned short*)(ws + WS_BH);
        unsigned short* xh = (unsigned short*)(ws + WS_XH);

        hipMemsetAsync(counts, 0, (size_t)NN * sizeof(unsigned), stream);
        k_cast_x<<<(NN * D / 8 + 255) / 256, 256, 0, stream>>>((const float4*)x, (uint4*)xh);
        k_cast_W<<<8, 256, 0, stream>>>(W, Bh);
        k_hist<<<(NE + 255) / 256, 256, 0, stream>>>(ei, counts);
        k_scan<<<NCHUNK, SCAN_CHUNK, 0, stream>>>(counts, row_ptr, partials);
        k_scan_partials<<<1, 128, 0, stream>>>(partials);
        k_add_offsets<<<NCHUNK, SCAN_CHUNK, 0, stream>>>(row_ptr, partials);
        k_place<<<(NE + 255) / 256, 256, 0, stream>>>(ei, row_ptr, counts, sorted);
        k_aggregate_h<<<(NN * 64 + 255) / 256, 256, 0, stream>>>(xh, row_ptr, sorted, out);
        gcn_gemm_mfma<<<ngemm, 256, 0, stream>>>(out, row_ptr, Bh, b);
    } else if (ws_size >= (size_t)WS_MID) {
        char* ws = (char*)d_ws;
        unsigned* counts   = (unsigned*)(ws + WS_COUNTS);
        unsigned* row_ptr  = (unsigned*)(ws + WS_ROWPTR);
        unsigned* partials = (unsigned*)(ws + WS_PARTIALS);
        unsigned* sorted   = (unsigned*)(ws + WS_SORTED);

        hipMemsetAsync(counts, 0, (size_t)NN * sizeof(unsigned), stream);
        k_hist<<<(NE + 255) / 256, 256, 0, stream>>>(ei, counts);
        k_scan<<<NCHUNK, SCAN_CHUNK, 0, stream>>>(counts, row_ptr, partials);
        k_scan_partials<<<1, 128, 0, stream>>>(partials);
        k_add_offsets<<<NCHUNK, SCAN_CHUNK, 0, stream>>>(row_ptr, partials);
        k_place<<<(NE + 255) / 256, 256, 0, stream>>>(ei, row_ptr, counts, sorted);
        k_aggregate<<<(NN * 64 + 255) / 256, 256, 0, stream>>>(x, row_ptr, sorted, out);
        gcn_gemm<true><<<ngemm, 256, 0, stream>>>(out, row_ptr, nullptr, W, b);
    } else {
        float* cnt = (float*)d_ws;
        hipMemsetAsync(d_out, 0, (size_t)NN * D * sizeof(float), stream);
        hipMemsetAsync(d_ws,  0, (size_t)NN * sizeof(float), stream);
        gcn_scatter<<<4096, 256, 0, stream>>>(x, ei, out, cnt);
        gcn_gemm<false><<<ngemm, 256, 0, stream>>>(out, nullptr, cnt, W, b);
    }
}

// Round 5
// 249.192 us; speedup vs baseline: 12.4029x; 1.1194x over previous
//
#include <hip/hip_runtime.h>

#define NN 100000
#define NE 1600000
#define D  128
#define SCAN_CHUNK 1024
#define NCHUNK ((NN + SCAN_CHUNK - 1) / SCAN_CHUNK)   // 98
#define NXCD 8
#define NPX  ((NN + NXCD - 1) / NXCD)                 // 12500 nodes per XCD slice

// ---- workspace layout (bytes) ----
#define WS_COUNTS   0u
#define WS_ROWPTR   400128u
#define WS_PARTIALS 800768u
#define WS_SORTED   801280u
#define WS_BH       7201280u                         // 16*128*8 bf16 = 32 KB
#define WS_XH       7234048u                         // NN*D bf16 = 25.6 MB
#define WS_MID      7201280u
#define WS_FULL     (7234048u + (unsigned)NN * (unsigned)D * 2u)  // 32,834,048

typedef __attribute__((ext_vector_type(8))) short bf16x8;
typedef __attribute__((ext_vector_type(4))) float f32x4;

__device__ __forceinline__ unsigned short f2bf(float f) {   // RNE f32 -> bf16
    union { float f; unsigned u; } v; v.f = f;
    unsigned r = v.u + 0x7fffu + ((v.u >> 16) & 1u);
    return (unsigned short)(r >> 16);
}
__device__ __forceinline__ float bfbits(unsigned hi) {      // bf16 bits in high half -> f32
    union { unsigned u; float f; } v; v.u = hi; return v.f;
}

// =============== CSR build (XCD-local scatter variants) ===============
// blockIdx%8 -> XCD (round-robin dispatch heuristic; perf-only, correctness
// independent). Each XCD group scans all edges, handles only its dst slice,
// so cursor atomics + sorted scatter stay resident in that XCD's L2.
__global__ __launch_bounds__(256) void k_hist_x(const int* __restrict__ ei,
                                                unsigned* __restrict__ counts) {
    const unsigned lo = (blockIdx.x & 7) * NPX;
    const int nth = (gridDim.x >> 3) * 256;
    const int tid = (blockIdx.x >> 3) * 256 + threadIdx.x;
    for (int e = tid; e < NE; e += nth) {
        unsigned d = (unsigned)ei[NE + e];
        if (d - lo < NPX) atomicAdd(&counts[d], 1u);
    }
}

__global__ __launch_bounds__(256) void k_place_x(const int* __restrict__ ei,
                                                 const unsigned* __restrict__ row_ptr,
                                                 unsigned* __restrict__ counts,
                                                 unsigned* __restrict__ sorted_src) {
    const unsigned lo = (blockIdx.x & 7) * NPX;
    const int nth = (gridDim.x >> 3) * 256;
    const int tid = (blockIdx.x >> 3) * 256 + threadIdx.x;
    for (int e = tid; e < NE; e += nth) {
        unsigned d = (unsigned)ei[NE + e];
        if (d - lo < NPX) {
            unsigned pos = row_ptr[d] + atomicSub(&counts[d], 1u) - 1u;
            sorted_src[pos] = (unsigned)ei[e];
        }
    }
}

// =============== scans ===============
__global__ __launch_bounds__(SCAN_CHUNK) void k_scan(const unsigned* __restrict__ counts,
                                                     unsigned* __restrict__ row_ptr,
                                                     unsigned* __restrict__ partials) {
    __shared__ unsigned s[SCAN_CHUNK];
    const int t = threadIdx.x;
    const int g = blockIdx.x * SCAN_CHUNK + t;
    unsigned v = (g < NN) ? counts[g] : 0u;
    s[t] = v;
    __syncthreads();
    for (int off = 1; off < SCAN_CHUNK; off <<= 1) {
        unsigned add = (t >= off) ? s[t - off] : 0u;
        __syncthreads();
        s[t] += add;
        __syncthreads();
    }
    if (g < NN) row_ptr[g] = s[t] - v;
    if (t == SCAN_CHUNK - 1) partials[blockIdx.x] = s[t];
}

__global__ __launch_bounds__(128) void k_scan_partials(unsigned* __restrict__ partials) {
    __shared__ unsigned s[128];
    const int t = threadIdx.x;
    unsigned v = (t < NCHUNK) ? partials[t] : 0u;
    s[t] = v;
    __syncthreads();
    for (int off = 1; off < 128; off <<= 1) {
        unsigned add = (t >= off) ? s[t - off] : 0u;
        __syncthreads();
        s[t] += add;
        __syncthreads();
    }
    if (t < NCHUNK) partials[t] = s[t] - v;
}

__global__ __launch_bounds__(SCAN_CHUNK) void k_add_offsets(unsigned* __restrict__ row_ptr,
                                                            const unsigned* __restrict__ partials) {
    const int g = blockIdx.x * SCAN_CHUNK + threadIdx.x;
    if (g < NN) row_ptr[g] += partials[blockIdx.x];
    if (g == 0) row_ptr[NN] = NE;
}

// =============== casts ===============
__global__ __launch_bounds__(256) void k_cast_x(const float4* __restrict__ x4,
                                                uint4* __restrict__ xh4) {
    int i = blockIdx.x * 256 + threadIdx.x;
    if (i >= NN * D / 8) return;
    const float4 v0 = x4[i * 2], v1 = x4[i * 2 + 1];
    uint4 o;
    o.x = f2bf(v0.x) | ((unsigned)f2bf(v0.y) << 16);
    o.y = f2bf(v0.z) | ((unsigned)f2bf(v0.w) << 16);
    o.z = f2bf(v1.x) | ((unsigned)f2bf(v1.y) << 16);
    o.w = f2bf(v1.z) | ((unsigned)f2bf(v1.w) << 16);
    xh4[i] = o;
}

__global__ __launch_bounds__(256) void k_cast_W(const float* __restrict__ W,
                                                unsigned short* __restrict__ Bh) {
    int idx = blockIdx.x * 256 + threadIdx.x;   // idx = j*16 + kc
    if (idx >= 128 * 16) return;
    int j = idx >> 4, kc = idx & 15;
    const float4 w0 = *(const float4*)(W + (size_t)j * D + kc * 8);
    const float4 w1 = *(const float4*)(W + (size_t)j * D + kc * 8 + 4);
    unsigned short* o = Bh + ((size_t)(kc * 128 + j)) * 8;
    o[0] = f2bf(w0.x); o[1] = f2bf(w0.y); o[2] = f2bf(w0.z); o[3] = f2bf(w0.w);
    o[4] = f2bf(w1.x); o[5] = f2bf(w1.y); o[6] = f2bf(w1.z); o[7] = f2bf(w1.w);
}

// =============== aggregation: wave/node, bf16 gather, XCD-swizzled node map ===============
// node = (blockIdx&7)*NPX + (blockIdx>>3)*4 + wave-in-block: waves read the
// sorted/row_ptr slice their own XCD just wrote (L2-dirty hits).
__global__ __launch_bounds__(256) void k_aggregate_hx(const unsigned short* __restrict__ xh,
                                                      const unsigned* __restrict__ rp,
                                                      const unsigned* __restrict__ srt,
                                                      float* __restrict__ agg) {
    const int wave = (blockIdx.x & 7) * NPX + (blockIdx.x >> 3) * 4 + (threadIdx.x >> 6);
    const int lane = threadIdx.x & 63;
    if (wave >= NN) return;
    const int half = lane >> 5;
    const int c8   = lane & 31;
    const unsigned b0 = rp[wave], b1 = rp[wave + 1];

    float a0=0.f,a1=0.f,a2=0.f,a3=0.f, c0=0.f,c1=0.f,c2=0.f,c3=0.f;
    unsigned i = b0 + half;
    for (; i + 6 < b1; i += 8) {
        const uint2 p0 = *(const uint2*)(xh + (size_t)srt[i]     * D + c8 * 4);
        const uint2 p1 = *(const uint2*)(xh + (size_t)srt[i + 2] * D + c8 * 4);
        const uint2 p2 = *(const uint2*)(xh + (size_t)srt[i + 4] * D + c8 * 4);
        const uint2 p3 = *(const uint2*)(xh + (size_t)srt[i + 6] * D + c8 * 4);
        a0 += bfbits(p0.x << 16); a1 += bfbits(p0.x & 0xffff0000u);
        a2 += bfbits(p0.y << 16); a3 += bfbits(p0.y & 0xffff0000u);
        c0 += bfbits(p1.x << 16); c1 += bfbits(p1.x & 0xffff0000u);
        c2 += bfbits(p1.y << 16); c3 += bfbits(p1.y & 0xffff0000u);
        a0 += bfbits(p2.x << 16); a1 += bfbits(p2.x & 0xffff0000u);
        a2 += bfbits(p2.y << 16); a3 += bfbits(p2.y & 0xffff0000u);
        c0 += bfbits(p3.x << 16); c1 += bfbits(p3.x & 0xffff0000u);
        c2 += bfbits(p3.y << 16); c3 += bfbits(p3.y & 0xffff0000u);
    }
    for (; i < b1; i += 2) {
        const uint2 p = *(const uint2*)(xh + (size_t)srt[i] * D + c8 * 4);
        a0 += bfbits(p.x << 16); a1 += bfbits(p.x & 0xffff0000u);
        a2 += bfbits(p.y << 16); a3 += bfbits(p.y & 0xffff0000u);
    }
    float s0 = a0 + c0, s1 = a1 + c1, s2 = a2 + c2, s3 = a3 + c3;
    s0 += __shfl_xor(s0, 32); s1 += __shfl_xor(s1, 32);
    s2 += __shfl_xor(s2, 32); s3 += __shfl_xor(s3, 32);
    if (half == 0)
        *(float4*)(agg + (size_t)wave * D + c8 * 4) = make_float4(s0, s1, s2, s3);
}

// =============== f32 aggregate (mid-path fallback) ===============
__global__ __launch_bounds__(256) void k_aggregate(const float* __restrict__ x,
                                                   const unsigned* __restrict__ row_ptr,
                                                   const unsigned* __restrict__ srt,
                                                   float* __restrict__ agg) {
    const int wave = (blockIdx.x * 256 + threadIdx.x) >> 6;
    const int lane = threadIdx.x & 63;
    if (wave >= NN) return;
    const unsigned b0 = row_ptr[wave], b1 = row_ptr[wave + 1];
    float2 a0 = make_float2(0.f, 0.f), a1 = make_float2(0.f, 0.f);
    float2 a2 = make_float2(0.f, 0.f), a3 = make_float2(0.f, 0.f);
    unsigned i = b0;
    for (; i + 4 <= b1; i += 4) {
        unsigned s0 = srt[i], s1 = srt[i + 1], s2 = srt[i + 2], s3 = srt[i + 3];
        const float2 v0 = *reinterpret_cast<const float2*>(x + (size_t)s0 * D + lane * 2);
        const float2 v1 = *reinterpret_cast<const float2*>(x + (size_t)s1 * D + lane * 2);
        const float2 v2 = *reinterpret_cast<const float2*>(x + (size_t)s2 * D + lane * 2);
        const float2 v3 = *reinterpret_cast<const float2*>(x + (size_t)s3 * D + lane * 2);
        a0.x += v0.x; a0.y += v0.y;
        a1.x += v1.x; a1.y += v1.y;
        a2.x += v2.x; a2.y += v2.y;
        a3.x += v3.x; a3.y += v3.y;
    }
    for (; i < b1; ++i) {
        unsigned s0 = srt[i];
        const float2 v0 = *reinterpret_cast<const float2*>(x + (size_t)s0 * D + lane * 2);
        a0.x += v0.x; a0.y += v0.y;
    }
    *reinterpret_cast<float2*>(agg + (size_t)wave * D + lane * 2) =
        make_float2(a0.x + a1.x + a2.x + a3.x, a0.y + a1.y + a2.y + a3.y);
}

// =============== fallback scatter (ws too small for CSR) ===============
__global__ __launch_bounds__(256) void gcn_scatter(
    const float* __restrict__ x, const int* __restrict__ ei,
    float* __restrict__ agg, float* __restrict__ cnt)
{
    int tid    = blockIdx.x * 256 + threadIdx.x;
    int lane   = tid & 31;
    int eg     = tid >> 5;
    int stride = (gridDim.x * 256) >> 5;
    for (int e = eg; e < NE; e += stride) {
        int src = ei[e];
        int dst = ei[NE + e];
        const float4 xv = *reinterpret_cast<const float4*>(x + (size_t)src * D + lane * 4);
        float* ap = agg + (size_t)dst * D + lane * 4;
        unsafeAtomicAdd(ap + 0, xv.x);
        unsafeAtomicAdd(ap + 1, xv.y);
        unsafeAtomicAdd(ap + 2, xv.z);
        unsafeAtomicAdd(ap + 3, xv.w);
        if (lane == 0) unsafeAtomicAdd(cnt + dst, 1.0f);
    }
}

// =============== MFMA finish GEMM (full path) ===============
__global__ __launch_bounds__(256) void gcn_gemm_mfma(
    float* __restrict__ io, const unsigned* __restrict__ rp,
    const unsigned short* __restrict__ Bh, const float* __restrict__ b)
{
    __shared__ unsigned short As[128 * 128];
    __shared__ unsigned short Bs[128 * 128];
    __shared__ float scs[128], hass[128], bbs[128];

    const int t  = threadIdx.x;
    const int nb = blockIdx.x * 128;

    {
        const uint4* src = (const uint4*)Bh;
        uint4* dst = (uint4*)Bs;
        #pragma unroll
        for (int i = 0; i < 8; ++i) dst[t + i * 256] = src[t + i * 256];
    }
    for (int gid = t; gid < 2048; gid += 256) {
        const int m = gid >> 4, g = gid & 15;
        const int node = nb + m;
        float4 v0 = make_float4(0.f,0.f,0.f,0.f), v1 = v0;
        if (node < NN) {
            v0 = *(const float4*)(io + (size_t)node * D + g * 8);
            v1 = *(const float4*)(io + (size_t)node * D + g * 8 + 4);
        }
        uint4 o;
        o.x = f2bf(v0.x) | ((unsigned)f2bf(v0.y) << 16);
        o.y = f2bf(v0.z) | ((unsigned)f2bf(v0.w) << 16);
        o.z = f2bf(v1.x) | ((unsigned)f2bf(v1.y) << 16);
        o.w = f2bf(v1.z) | ((unsigned)f2bf(v1.w) << 16);
        *(uint4*)(As + (size_t)m * 128 + ((g ^ (m & 15)) * 8)) = o;
    }
    if (t < 128) {
        const int node = nb + t;
        float c = (node < NN) ? (float)(rp[node + 1] - rp[node]) : 0.f;
        scs[t]  = 1.f / fmaxf(c, 1.f);
        hass[t] = (c > 0.f) ? 1.f : 0.f;
        bbs[t]  = b[t];
    }
    __syncthreads();

    const int w = t >> 6, lane = t & 63;
    const int wm = (w & 1) * 64, wn = (w >> 1) * 64;
    const int lr = lane & 15, lc = lane >> 4;

    f32x4 acc[4][4];
    #pragma unroll
    for (int mi = 0; mi < 4; ++mi)
        #pragma unroll
        for (int ni = 0; ni < 4; ++ni) acc[mi][ni] = (f32x4){0.f, 0.f, 0.f, 0.f};

    #pragma unroll
    for (int ks = 0; ks < 4; ++ks) {
        bf16x8 af[4], bg[4];
        #pragma unroll
        for (int mi = 0; mi < 4; ++mi) {
            const int m = wm + mi * 16 + lr;
            const int g = ks * 4 + lc;
            af[mi] = *(const bf16x8*)(As + (size_t)m * 128 + ((g ^ (m & 15)) * 8));
        }
        #pragma unroll
        for (int ni = 0; ni < 4; ++ni) {
            const int j  = wn + ni * 16 + lr;
            const int kc = ks * 4 + lc;
            bg[ni] = *(const bf16x8*)(Bs + ((size_t)(kc * 128 + j)) * 8);
        }
        #pragma unroll
        for (int mi = 0; mi < 4; ++mi)
            #pragma unroll
            for (int ni = 0; ni < 4; ++ni)
                acc[mi][ni] = __builtin_amdgcn_mfma_f32_16x16x32_bf16(
                    af[mi], bg[ni], acc[mi][ni], 0, 0, 0);
    }

    #pragma unroll
    for (int mi = 0; mi < 4; ++mi) {
        #pragma unroll
        for (int reg = 0; reg < 4; ++reg) {
            const int rl   = wm + mi * 16 + lc * 4 + reg;
            const int node = nb + rl;
            if (node >= NN) continue;
            const float s = scs[rl], hf = hass[rl];
            #pragma unroll
            for (int ni = 0; ni < 4; ++ni) {
                const int jl = wn + ni * 16 + lr;
                io[(size_t)node * D + jl] =
                    fmaxf(fmaf(acc[mi][ni][reg], s, bbs[jl] * hf), 0.f);
            }
        }
    }
}

// =============== VALU finish GEMM (fallback paths) ===============
template <bool USE_ROWPTR>
__global__ __launch_bounds__(256, 1) void gcn_gemm(
    float* __restrict__ io, const unsigned* __restrict__ rp,
    const float* __restrict__ cnt,
    const float* __restrict__ W, const float* __restrict__ b)
{
    __shared__ float At[128 * 128];
    __shared__ float Wt[128 * 128];
    __shared__ float sc[128];
    __shared__ float hasf[128];

    const int t  = threadIdx.x;
    const int nb = blockIdx.x * 128;

    for (int i = t; i < 128 * 32; i += 256) {
        int j = i >> 5, c4 = i & 31;
        const float4 v = *reinterpret_cast<const float4*>(W + (size_t)j * D + c4 * 4);
        int k0 = c4 * 4;
        Wt[(k0 + 0) * 128 + (j ^ (((k0 + 0) & 12) << 1))] = v.x;
        Wt[(k0 + 1) * 128 + (j ^ (((k0 + 1) & 12) << 1))] = v.y;
        Wt[(k0 + 2) * 128 + (j ^ (((k0 + 2) & 12) << 1))] = v.z;
        Wt[(k0 + 3) * 128 + (j ^ (((k0 + 3) & 12) << 1))] = v.w;
    }
    for (int i = t; i < 128 * 32; i += 256) {
        int n = i >> 5, c4 = i & 31;
        int node = nb + n;
        float4 v = make_float4(0.f, 0.f, 0.f, 0.f);
        if (node < NN)
            v = *reinterpret_cast<const float4*>(io + (size_t)node * D + c4 * 4);
        int k0 = c4 * 4;
        At[(k0 + 0) * 128 + (n ^ (((k0 + 0) & 12) << 1))] = v.x;
        At[(k0 + 1) * 128 + (n ^ (((k0 + 1) & 12) << 1))] = v.y;
        At[(k0 + 2) * 128 + (n ^ (((k0 + 2) & 12) << 1))] = v.z;
        At[(k0 + 3) * 128 + (n ^ (((k0 + 3) & 12) << 1))] = v.w;
    }
    if (t < 128) {
        int node = nb + t;
        float c = 0.f;
        if (node < NN)
            c = USE_ROWPTR ? (float)(rp[node + 1] - rp[node]) : cnt[node];
        sc[t]   = 1.0f / fmaxf(c, 1.0f);
        hasf[t] = (c > 0.f) ? 1.0f : 0.0f;
    }
    __syncthreads();

    const int tn = t >> 4;
    const int tj = t & 15;

    float bj[8];
    {
        const float4 b0 = *reinterpret_cast<const float4*>(b + tj * 8);
        const float4 b1 = *reinterpret_cast<const float4*>(b + tj * 8 + 4);
        bj[0]=b0.x; bj[1]=b0.y; bj[2]=b0.z; bj[3]=b0.w;
        bj[4]=b1.x; bj[5]=b1.y; bj[6]=b1.z; bj[7]=b1.w;
    }

    float acc[8][8];
    #pragma unroll
    for (int i = 0; i < 8; ++i)
        #pragma unroll
        for (int j = 0; j < 8; ++j) acc[i][j] = 0.f;

    #pragma unroll 2
    for (int k = 0; k < 128; ++k) {
        const int g = (k & 12) << 1;
        const float* Ar = At + k * 128;
        const float* Wr = Wt + k * 128;
        const float4 a0 = *reinterpret_cast<const float4*>(Ar + ((tn * 8) ^ g));
        const float4 a1 = *reinterpret_cast<const float4*>(Ar + ((tn * 8 + 4) ^ g));
        const float4 w0 = *reinterpret_cast<const float4*>(Wr + ((tj * 8) ^ g));
        const float4 w1 = *reinterpret_cast<const float4*>(Wr + ((tj * 8 + 4) ^ g));
        const float a[8] = {a0.x,a0.y,a0.z,a0.w,a1.x,a1.y,a1.z,a1.w};
        const float wv[8] = {w0.x,w0.y,w0.z,w0.w,w1.x,w1.y,w1.z,w1.w};
        #pragma unroll
        for (int i = 0; i < 8; ++i)
            #pragma unroll
            for (int j = 0; j < 8; ++j)
                acc[i][j] = fmaf(a[i], wv[j], acc[i][j]);
    }

    #pragma unroll
    for (int i = 0; i < 8; ++i) {
        const int node = nb + tn * 8 + i;
        if (node >= NN) continue;
        const float s  = sc[tn * 8 + i];
        const float hf = hasf[tn * 8 + i];
        float r[8];
        #pragma unroll
        for (int j = 0; j < 8; ++j)
            r[j] = fmaxf(fmaf(acc[i][j], s, bj[j] * hf), 0.f);
        float4* orow = reinterpret_cast<float4*>(io + (size_t)node * D + tj * 8);
        orow[0] = make_float4(r[0], r[1], r[2], r[3]);
        orow[1] = make_float4(r[4], r[5], r[6], r[7]);
    }
}

extern "C" void kernel_launch(void* const* d_in, const int* in_sizes, int n_in,
                              void* d_out, int out_size, void* d_ws, size_t ws_size,
                              hipStream_t stream)
{
    const float* x  = (const float*)d_in[0];
    const int*   ei = (const int*)d_in[1];
    // d_in[2] = edge_features: unused by the reference computation
    const float* W  = (const float*)d_in[3];
    const float* b  = (const float*)d_in[4];
    float* out = (float*)d_out;            // doubles as the aggregation buffer

    const int ngemm = (NN + 127) / 128;

    if (ws_size >= (size_t)WS_FULL) {
        char* ws = (char*)d_ws;
        unsigned* counts   = (unsigned*)(ws + WS_COUNTS);
        unsigned* row_ptr  = (unsigned*)(ws + WS_ROWPTR);
        unsigned* partials = (unsigned*)(ws + WS_PARTIALS);
        unsigned* sorted   = (unsigned*)(ws + WS_SORTED);
        unsigned short* Bh = (unsigned short*)(ws + WS_BH);
        unsigned short* xh = (unsigned short*)(ws + WS_XH);

        hipMemsetAsync(counts, 0, (size_t)NN * sizeof(unsigned), stream);
        k_cast_x<<<(NN * D / 8 + 255) / 256, 256, 0, stream>>>((const float4*)x, (uint4*)xh);
        k_cast_W<<<8, 256, 0, stream>>>(W, Bh);
        k_hist_x<<<2048, 256, 0, stream>>>(ei, counts);
        k_scan<<<NCHUNK, SCAN_CHUNK, 0, stream>>>(counts, row_ptr, partials);
        k_scan_partials<<<1, 128, 0, stream>>>(partials);
        k_add_offsets<<<NCHUNK, SCAN_CHUNK, 0, stream>>>(row_ptr, partials);
        k_place_x<<<2048, 256, 0, stream>>>(ei, row_ptr, counts, sorted);
        k_aggregate_hx<<<((NPX + 3) / 4) * 8, 256, 0, stream>>>(xh, row_ptr, sorted, out);
        gcn_gemm_mfma<<<ngemm, 256, 0, stream>>>(out, row_ptr, Bh, b);
    } else if (ws_size >= (size_t)WS_MID) {
        char* ws = (char*)d_ws;
        unsigned* counts   = (unsigned*)(ws + WS_COUNTS);
        unsigned* row_ptr  = (unsigned*)(ws + WS_ROWPTR);
        unsigned* partials = (unsigned*)(ws + WS_PARTIALS);
        unsigned* sorted   = (unsigned*)(ws + WS_SORTED);

        hipMemsetAsync(counts, 0, (size_t)NN * sizeof(unsigned), stream);
        k_hist_x<<<2048, 256, 0, stream>>>(ei, counts);
        k_scan<<<NCHUNK, SCAN_CHUNK, 0, stream>>>(counts, row_ptr, partials);
        k_scan_partials<<<1, 128, 0, stream>>>(partials);
        k_add_offsets<<<NCHUNK, SCAN_CHUNK, 0, stream>>>(row_ptr, partials);
        k_place_x<<<2048, 256, 0, stream>>>(ei, row_ptr, counts, sorted);
        k_aggregate<<<(NN * 64 + 255) / 256, 256, 0, stream>>>(x, row_ptr, sorted, out);
        gcn_gemm<true><<<ngemm, 256, 0, stream>>>(out, row_ptr, nullptr, W, b);
    } else {
        float* cnt = (float*)d_ws;
        hipMemsetAsync(d_out, 0, (size_t)NN * D * sizeof(float), stream);
        hipMemsetAsync(d_ws,  0, (size_t)NN * sizeof(float), stream);
        gcn_scatter<<<4096, 256, 0, stream>>>(x, ei, out, cnt);
        gcn_gemm<false><<<ngemm, 256, 0, stream>>>(out, nullptr, cnt, W, b);
    }
}